// Round 17
// baseline (117.133 us; speedup 1.0000x reference)
//
#include <hip/hip_runtime.h>
#include <hip/hip_bf16.h>

#define NN 8192
#define IN_F 256
#define OF 128

typedef float  f32x4   __attribute__((ext_vector_type(4)));
typedef short  short4v __attribute__((ext_vector_type(4)));
typedef short  short8v __attribute__((ext_vector_type(8)));
typedef int    int4v   __attribute__((ext_vector_type(4)));
typedef __bf16 bf16x8v __attribute__((ext_vector_type(8)));
typedef unsigned long long u64;

__device__ __forceinline__ unsigned short bf16_bits(float x) {
    __bf16 b = (__bf16)x;
    return __builtin_bit_cast(unsigned short, b);
}

// K=32 bf16 MFMA (gfx950): A row=lane&15, k=8*(lane>>4)+e; B col=lane&15,
// k=8*(lane>>4)+e; D col=lane&15, row=4*(lane>>4)+q  (m89-verified family).
__device__ __forceinline__ f32x4 mfma32(short8v a, short8v b, f32x4 c) {
#if __has_builtin(__builtin_amdgcn_mfma_f32_16x16x32_bf16)
    return __builtin_amdgcn_mfma_f32_16x16x32_bf16(
        __builtin_bit_cast(bf16x8v, a), __builtin_bit_cast(bf16x8v, b), c, 0, 0, 0);
#else
    asm("v_mfma_f32_16x16x32_bf16 %0, %1, %2, %0" : "+v"(c) : "v"(a), "v"(b));
    return c;
#endif
}

// async global->LDS, 16B per lane; LDS dest = wave-uniform base + lane*16
__device__ __forceinline__ void gload_lds16(const void* gsrc, void* lds) {
    __builtin_amdgcn_global_load_lds(
        (const __attribute__((address_space(1))) int*)gsrc,
        (__attribute__((address_space(3))) int*)lds, 16, 0, 0);
}

// ---------------------------------------------------------------------------
// Kernel A: h = X @ W (f32, LDS-staged W).  Emits HtB in K=32 B-fragment
// order: for h[j][f]:  kt=j>>5, g=(j>>3)&3, e=j&7, np=f>>4, c=f&15
//   short index = ((kt*8 + np)*64 + g*16 + c)*8 + e      (8 KB per kt)
// Also f_src = h.a[:OF], f_dst = h.a[OF:].
// ---------------------------------------------------------------------------
__global__ __launch_bounds__(256) void gat_prep(
    const float* __restrict__ X, const float* __restrict__ W,
    const float* __restrict__ a, unsigned short* __restrict__ HtB,
    float* __restrict__ f_src, float* __restrict__ f_dst)
{
    __shared__ float Wlds[IN_F * OF];   // 128 KiB
    __shared__ float red_s[32][8];
    __shared__ float red_d[32][8];

    const int t = threadIdx.x;
    {
        const f32x4* Wv = (const f32x4*)W;
        f32x4*       Wl = (f32x4*)Wlds;
        #pragma unroll
        for (int c = 0; c < 32; ++c) Wl[c * 256 + t] = Wv[c * 256 + t];
    }
    __syncthreads();

    const int row = t & 31;
    const int sub = t >> 5;            // feature block np = sub (16 feats)
    const int i   = blockIdx.x * 32 + row;

    f32x4 acc[4] = {};
    const float* xrow = X + (size_t)i * IN_F;

    #pragma unroll 4
    for (int kk = 0; kk < IN_F; kk += 4) {
        f32x4 xv = *(const f32x4*)(xrow + kk);
        #pragma unroll
        for (int e = 0; e < 4; ++e) {
            const f32x4* wr = (const f32x4*)(Wlds + (kk + e) * OF + sub * 16);
            float xs = xv[e];
            #pragma unroll
            for (int c4 = 0; c4 < 4; ++c4) acc[c4] += xs * wr[c4];
        }
    }

    const int kt = i >> 5;
    const int gq = (i >> 3) & 3;
    const int eq = i & 7;

    float ps = 0.f, pd = 0.f;
    #pragma unroll
    for (int c4 = 0; c4 < 4; ++c4) {
        #pragma unroll
        for (int e = 0; e < 4; ++e) {
            float v = acc[c4][e];
            int   c = c4 * 4 + e;      // 0..15 within feature block
            ps += v * a[sub * 16 + c];
            pd += v * a[OF + sub * 16 + c];
            HtB[(size_t)(((kt * 8 + sub) * 64) + gq * 16 + c) * 8 + eq]
                = bf16_bits(v);
        }
    }
    red_s[row][sub] = ps;
    red_d[row][sub] = pd;
    __syncthreads();
    if (t < 32) {
        float s = 0.f;
        #pragma unroll
        for (int s8 = 0; s8 < 8; ++s8) s += red_s[t][s8];
        f_src[blockIdx.x * 32 + t] = s;
    } else if (t < 64) {
        const int r2 = t - 32;
        float s = 0.f;
        #pragma unroll
        for (int s8 = 0; s8 < 8; ++s8) s += red_d[r2][s8];
        f_dst[blockIdx.x * 32 + r2] = s;
    }
}

// ---------------------------------------------------------------------------
// gat_pack: adj (int32 0/1, 256 MB) -> bitmask (8 MB).  Pure stream at
// fill-rate (verified R8/R13).  Read back as u32[8192][256]:
// u32[i][q] bit c = adj[i][q*32+c].
// ---------------------------------------------------------------------------
__global__ __launch_bounds__(256) void gat_pack(
    const int* __restrict__ adj, u64* __restrict__ bits)
{
    const int tid  = threadIdx.x;
    const int wave = tid >> 6;
    const int lane = tid & 63;
    const int row  = blockIdx.x * 4 + wave;

    const int* arow = adj + (size_t)row * NN + lane;
    u64* brow = bits + (size_t)row * (NN / 64);

    #pragma unroll 2
    for (int it = 0; it < 32; ++it) {
        const int c0 = it * 256;
        const int v0 = arow[c0];
        const int v1 = arow[c0 + 64];
        const int v2 = arow[c0 + 128];
        const int v3 = arow[c0 + 192];
        const u64 m0 = __ballot(v0 != 0);
        const u64 m1 = __ballot(v1 != 0);
        const u64 m2 = __ballot(v2 != 0);
        const u64 m3 = __ballot(v3 != 0);
        if (lane == 0) {
            brow[it * 4 + 0] = m0;
            brow[it * 4 + 1] = m1;
            brow[it * 4 + 2] = m2;
            brow[it * 4 + 3] = m3;
        }
    }
}

// ---------------------------------------------------------------------------
// gat_row3b (v17): row3 structure (R16) with the adj HBM stream REMOVED --
// A-side masks come from the 8 MB L2-resident bitmask.  Single-variable
// ablation vs R16: everything else identical.
// Grid = 32 row-blocks x 8 k-splits = 256 blocks (1/CU) x 512 threads.
// Wave w owns rows rowbase+w*32..+31; K-range = ks*1024..+1023 = 32 kt32;
// 4 supersteps x 8 kt32 (64 KB B slab, double-buffered, 128 KiB LDS).
// Per kt32/wave: 2 u32 bit loads + 2 f_dst f32x4 + 8 ds_read_b128 +
// 16 exp + 16 MFMA(16x16x32).
// ---------------------------------------------------------------------------
__global__ __launch_bounds__(512, 2) void gat_row3b(
    const unsigned int* __restrict__ bits32, const char* __restrict__ htb,
    const float* __restrict__ f_src, const float* __restrict__ f_dst,
    float* __restrict__ part, float* __restrict__ rsPart)
{
    __shared__ __align__(16) char smem[131072];   // 2 x 64KiB dbuf; epilogue lt

    const int tid  = threadIdx.x;
    const int w    = tid >> 6;
    const int lane = tid & 63;
    const int r    = lane & 15;
    const int g    = lane >> 4;
    const int ms   = blockIdx.x >> 3;
    const int ks   = blockIdx.x & 7;
    const int rowbase = ms * 256;
    const int row0 = rowbase + w * 32 + r;
    const int row1 = row0 + 16;

    const float fsrc0 = f_src[row0];
    const float fsrc1 = f_src[row1];
    const unsigned int* bptr0 = bits32 + (size_t)row0 * (NN / 32) + ks * 32;
    const unsigned int* bptr1 = bits32 + (size_t)row1 * (NN / 32) + ks * 32;
    const float* fptr  = f_dst + ks * 1024 + g * 8;
    const char*  gB    = htb + (size_t)ks * 262144;   // 32 kt32 x 8 KB

    f32x4 acc0[8] = {};
    f32x4 acc1[8] = {};
    float psum0 = 0.f, psum1 = 0.f;

    // prologue: stage superstep 0 into buf 0 (64 KB, linear; 8 x 16B/thread)
    #pragma unroll
    for (int u = 0; u < 8; ++u)
        gload_lds16(gB + (size_t)(u * 512 + tid) * 16,
                    smem + (size_t)(u * 512 + tid) * 16);

    int buf = 0;
    for (int ss = 0; ss < 4; ++ss) {
        __syncthreads();   // stage(ss) resident (vmcnt drain); buf^1 free

        if (ss + 1 < 4) {
            const char* gs = gB + (size_t)(ss + 1) * 65536;
            #pragma unroll
            for (int u = 0; u < 8; ++u)
                gload_lds16(gs + (size_t)(u * 512 + tid) * 16,
                            smem + (buf ^ 1) * 65536 + (size_t)(u * 512 + tid) * 16);
        }

        #pragma unroll
        for (int ktl = 0; ktl < 8; ++ktl) {
            const int i = ss * 8 + ktl;          // kt32 local index 0..31

            const unsigned int bu0 = bptr0[i];
            const unsigned int bu1 = bptr1[i];
            const f32x4 fd0 = *(const f32x4*)(fptr + i * 32);
            const f32x4 fd1 = *(const f32x4*)(fptr + i * 32 + 4);

            const char* lb = smem + buf * 65536 + ktl * 8192 + (size_t)lane * 16;
            short8v bv[8];
            #pragma unroll
            for (int np = 0; np < 8; ++np)
                bv[np] = *(const short8v*)(lb + np * 1024);

            const unsigned int sh0 = bu0 >> (g * 8);
            const unsigned int sh1 = bu1 >> (g * 8);
            float p0[8], p1[8];
            #pragma unroll
            for (int e = 0; e < 4; ++e) {
                float s;
                s = fsrc0 + fd0[e]; s = s > 0.f ? s : 0.2f * s;
                p0[e]     = (sh0 & (1u << e))       ? __expf(s) : 0.f;
                s = fsrc0 + fd1[e]; s = s > 0.f ? s : 0.2f * s;
                p0[4 + e] = (sh0 & (1u << (4 + e))) ? __expf(s) : 0.f;
                s = fsrc1 + fd0[e]; s = s > 0.f ? s : 0.2f * s;
                p1[e]     = (sh1 & (1u << e))       ? __expf(s) : 0.f;
                s = fsrc1 + fd1[e]; s = s > 0.f ? s : 0.2f * s;
                p1[4 + e] = (sh1 & (1u << (4 + e))) ? __expf(s) : 0.f;
            }
            psum0 += ((p0[0] + p0[1]) + (p0[2] + p0[3]))
                   + ((p0[4] + p0[5]) + (p0[6] + p0[7]));
            psum1 += ((p1[0] + p1[1]) + (p1[2] + p1[3]))
                   + ((p1[4] + p1[5]) + (p1[6] + p1[7]));
            const short8v af0 = { (short)bf16_bits(p0[0]), (short)bf16_bits(p0[1]),
                                  (short)bf16_bits(p0[2]), (short)bf16_bits(p0[3]),
                                  (short)bf16_bits(p0[4]), (short)bf16_bits(p0[5]),
                                  (short)bf16_bits(p0[6]), (short)bf16_bits(p0[7]) };
            const short8v af1 = { (short)bf16_bits(p1[0]), (short)bf16_bits(p1[1]),
                                  (short)bf16_bits(p1[2]), (short)bf16_bits(p1[3]),
                                  (short)bf16_bits(p1[4]), (short)bf16_bits(p1[5]),
                                  (short)bf16_bits(p1[6]), (short)bf16_bits(p1[7]) };

            #pragma unroll
            for (int np = 0; np < 8; ++np) {
                acc0[np] = mfma32(af0, bv[np], acc0[np]);
                acc1[np] = mfma32(af1, bv[np], acc1[np]);
            }
        }
        buf ^= 1;
    }

    // rowsum partials: reduce over the 4 g-groups; lanes 0-15 store direct
    psum0 += __shfl_xor(psum0, 16, 64);
    psum0 += __shfl_xor(psum0, 32, 64);
    psum1 += __shfl_xor(psum1, 16, 64);
    psum1 += __shfl_xor(psum1, 32, 64);
    if (lane < 16) {
        rsPart[(size_t)ks * NN + rowbase + w * 32 + lane]      = psum0;
        rsPart[(size_t)ks * NN + rowbase + w * 32 + 16 + lane] = psum1;
    }

    __syncthreads();   // all waves done reading stage buffers

    // wave-private LDS transpose (frag -> row-major 32x128), then coalesced
    float* lt = (float*)(smem + w * 16384);   // 16 KiB per wave
    #pragma unroll
    for (int np = 0; np < 8; ++np)
        #pragma unroll
        for (int q = 0; q < 4; ++q) {
            lt[(4 * g + q) * OF + np * 16 + r]        = acc0[np][q];
            lt[2048 + (4 * g + q) * OF + np * 16 + r] = acc1[np][q];
        }

    float* pb = part + ((size_t)ks * NN + rowbase + w * 32) * OF;
    #pragma unroll
    for (int j = 0; j < 16; ++j) {
        const int idx = j * 64 + lane;       // f32x4 index in 32x128 tile
        *(f32x4*)(pb + (size_t)idx * 4) = *(const f32x4*)&lt[idx * 4];
    }
}

// ---------------------------------------------------------------------------
// Finish: out = relu( (sum_ks part[ks]) / (sum_ks rs[ks]) ).
// ---------------------------------------------------------------------------
__global__ __launch_bounds__(512) void gat_finish(
    const float* __restrict__ part, const float* __restrict__ rsPart,
    float* __restrict__ out)
{
    const int tg  = blockIdx.x * 512 + threadIdx.x;   // f32x4 index
    const int row = tg >> 5;

    f32x4 v = {};
    float den = 0.f;
    #pragma unroll
    for (int ks = 0; ks < 8; ++ks) {
        v   += *(const f32x4*)(part + (size_t)ks * NN * OF + (size_t)tg * 4);
        den += rsPart[(size_t)ks * NN + row];
    }
    const float inv = 1.0f / den;
    f32x4 o = v * inv;
    #pragma unroll
    for (int e = 0; e < 4; ++e) o[e] = fmaxf(o[e], 0.f);
    *(f32x4*)(out + (size_t)tg * 4) = o;
}

extern "C" void kernel_launch(void* const* d_in, const int* in_sizes, int n_in,
                              void* d_out, int out_size, void* d_ws, size_t ws_size,
                              hipStream_t stream) {
    const float* X   = (const float*)d_in[0];
    const int*   adj = (const int*)d_in[1];
    const float* W   = (const float*)d_in[2];
    const float* a   = (const float*)d_in[3];
    float* out = (float*)d_out;

    char* ws = (char*)d_ws;
    unsigned short* HtB    = (unsigned short*)ws;                  // 2 MiB
    float*          f_src  = (float*)(ws + 2097152);               // 32 KiB
    float*          f_dst  = (float*)(ws + 2097152 + 32768);       // 32 KiB
    u64*            bits   = (u64*)(ws + 2162688);                 // 8 MiB
    float*          rsPart = (float*)(ws + 10551296);              // 256 KiB
    float*          part   = (float*)(ws + 10813440);              // 32 MiB

    gat_pack<<<NN / 4, 256, 0, stream>>>(adj, bits);
    gat_prep<<<NN / 32, 256, 0, stream>>>(X, W, a, HtB, f_src, f_dst);
    gat_row3b<<<256, 512, 0, stream>>>((const unsigned int*)bits, (const char*)HtB,
                                       f_src, f_dst, part, rsPart);
    gat_finish<<<512, 512, 0, stream>>>(part, rsPart, out);
}

// Round 18
// 96.353 us; speedup vs baseline: 1.2157x; 1.2157x over previous
//
#include <hip/hip_runtime.h>
#include <hip/hip_bf16.h>

#define NN 8192
#define IN_F 256
#define OF 128

typedef float  f32x4   __attribute__((ext_vector_type(4)));
typedef short  short4v __attribute__((ext_vector_type(4)));
typedef short  short8v __attribute__((ext_vector_type(8)));
typedef int    int4v   __attribute__((ext_vector_type(4)));
typedef __bf16 bf16x8v __attribute__((ext_vector_type(8)));

__device__ __forceinline__ unsigned short bf16_bits(float x) {
    __bf16 b = (__bf16)x;
    return __builtin_bit_cast(unsigned short, b);
}

// K=32 bf16 MFMA (gfx950): A row=lane&15, k=8*(lane>>4)+e; B col=lane&15,
// k=8*(lane>>4)+e; D col=lane&15, row=4*(lane>>4)+q  (m89-verified family).
__device__ __forceinline__ f32x4 mfma32(short8v a, short8v b, f32x4 c) {
#if __has_builtin(__builtin_amdgcn_mfma_f32_16x16x32_bf16)
    return __builtin_amdgcn_mfma_f32_16x16x32_bf16(
        __builtin_bit_cast(bf16x8v, a), __builtin_bit_cast(bf16x8v, b), c, 0, 0, 0);
#else
    asm("v_mfma_f32_16x16x32_bf16 %0, %1, %2, %0" : "+v"(c) : "v"(a), "v"(b));
    return c;
#endif
}

// async global->LDS, 16B per lane; LDS dest = wave-uniform base + lane*16
__device__ __forceinline__ void gload_lds16(const void* gsrc, void* lds) {
    __builtin_amdgcn_global_load_lds(
        (const __attribute__((address_space(1))) int*)gsrc,
        (__attribute__((address_space(3))) int*)lds, 16, 0, 0);
}

// ---------------------------------------------------------------------------
// Kernel A: h = X @ W (f32, LDS-staged W).  Emits HtB in K=32 B-fragment
// order: for h[j][f]:  kt=j>>5, g=(j>>3)&3, e=j&7, np=f>>4, c=f&15
//   short index = ((kt*8 + np)*64 + g*16 + c)*8 + e      (8 KB per kt)
// Also f_src = h.a[:OF], f_dst = h.a[OF:].
// ---------------------------------------------------------------------------
__global__ __launch_bounds__(256) void gat_prep(
    const float* __restrict__ X, const float* __restrict__ W,
    const float* __restrict__ a, unsigned short* __restrict__ HtB,
    float* __restrict__ f_src, float* __restrict__ f_dst)
{
    __shared__ float Wlds[IN_F * OF];   // 128 KiB
    __shared__ float red_s[32][8];
    __shared__ float red_d[32][8];

    const int t = threadIdx.x;
    {
        const f32x4* Wv = (const f32x4*)W;
        f32x4*       Wl = (f32x4*)Wlds;
        #pragma unroll
        for (int c = 0; c < 32; ++c) Wl[c * 256 + t] = Wv[c * 256 + t];
    }
    __syncthreads();

    const int row = t & 31;
    const int sub = t >> 5;            // feature block np = sub (16 feats)
    const int i   = blockIdx.x * 32 + row;

    f32x4 acc[4] = {};
    const float* xrow = X + (size_t)i * IN_F;

    #pragma unroll 4
    for (int kk = 0; kk < IN_F; kk += 4) {
        f32x4 xv = *(const f32x4*)(xrow + kk);
        #pragma unroll
        for (int e = 0; e < 4; ++e) {
            const f32x4* wr = (const f32x4*)(Wlds + (kk + e) * OF + sub * 16);
            float xs = xv[e];
            #pragma unroll
            for (int c4 = 0; c4 < 4; ++c4) acc[c4] += xs * wr[c4];
        }
    }

    const int kt = i >> 5;
    const int gq = (i >> 3) & 3;
    const int eq = i & 7;

    float ps = 0.f, pd = 0.f;
    #pragma unroll
    for (int c4 = 0; c4 < 4; ++c4) {
        #pragma unroll
        for (int e = 0; e < 4; ++e) {
            float v = acc[c4][e];
            int   c = c4 * 4 + e;      // 0..15 within feature block
            ps += v * a[sub * 16 + c];
            pd += v * a[OF + sub * 16 + c];
            HtB[(size_t)(((kt * 8 + sub) * 64) + gq * 16 + c) * 8 + eq]
                = bf16_bits(v);
        }
    }
    red_s[row][sub] = ps;
    red_d[row][sub] = pd;
    __syncthreads();
    if (t < 32) {
        float s = 0.f;
        #pragma unroll
        for (int s8 = 0; s8 < 8; ++s8) s += red_s[t][s8];
        f_src[blockIdx.x * 32 + t] = s;
    } else if (t < 64) {
        const int r2 = t - 32;
        float s = 0.f;
        #pragma unroll
        for (int s8 = 0; s8 < 8; ++s8) s += red_d[r2][s8];
        f_dst[blockIdx.x * 32 + r2] = s;
    }
}

// ---------------------------------------------------------------------------
// gat_row3c (v18): R16's best structure + two latency cuts:
//   (1) f_dst slice (4 KB) preloaded to LDS -> in-loop fd reads are ds_read
//   (2) adj depth-1 register pipeline inside the unrolled superstep body
// Grid = 32 row-blocks x 8 k-splits = 256 blocks (1/CU) x 512 threads.
// Wave w owns rows rowbase+w*32..+31 (two 16-row groups sharing B reads).
// K-range = ks*1024..+1023 = 32 kt32; 4 supersteps x 8 kt32 (64 KB B slab,
// double-buffered via global_load_lds; 132 KiB LDS total).
// ---------------------------------------------------------------------------
__global__ __launch_bounds__(512, 2) void gat_row3c(
    const int* __restrict__ adj, const char* __restrict__ htb,
    const float* __restrict__ f_src, const float* __restrict__ f_dst,
    float* __restrict__ part, float* __restrict__ rsPart)
{
    __shared__ __align__(16) char smem[135168];
    // [0,131072): 2 x 64KiB B dbuf (epilogue: lt per wave)
    // [131072, 135168): f_dst slice (1024 f32)

    const int tid  = threadIdx.x;
    const int w    = tid >> 6;
    const int lane = tid & 63;
    const int r    = lane & 15;
    const int g    = lane >> 4;
    const int ms   = blockIdx.x >> 3;
    const int ks   = blockIdx.x & 7;
    const int rowbase = ms * 256;
    const int row0 = rowbase + w * 32 + r;
    const int row1 = row0 + 16;

    const float fsrc0 = f_src[row0];
    const float fsrc1 = f_src[row1];
    const int*   aptr0 = adj + (size_t)row0 * NN + ks * 1024 + g * 8;
    const int*   aptr1 = adj + (size_t)row1 * NN + ks * 1024 + g * 8;
    const char*  gB    = htb + (size_t)ks * 262144;   // 32 kt32 x 8 KB

    float* fdl = (float*)(smem + 131072);

    // preload f_dst slice (4 KB) into LDS; covered by the loop-top barrier
    if (tid < 256)
        *((f32x4*)fdl + tid) = *((const f32x4*)(f_dst + ks * 1024) + tid);

    f32x4 acc0[8] = {};
    f32x4 acc1[8] = {};
    float psum0 = 0.f, psum1 = 0.f;

    // prologue: stage superstep 0 into buf 0 (64 KB, linear; 8 x 16B/thread)
    #pragma unroll
    for (int u = 0; u < 8; ++u)
        gload_lds16(gB + (size_t)(u * 512 + tid) * 16,
                    smem + (size_t)(u * 512 + tid) * 16);

    // adj depth-1 pipeline: current regs for kt32 index 0
    int4v ca0 = *(const int4v*)(aptr0);
    int4v ca1 = *(const int4v*)(aptr0 + 4);
    int4v ca2 = *(const int4v*)(aptr1);
    int4v ca3 = *(const int4v*)(aptr1 + 4);

    int buf = 0;
    for (int ss = 0; ss < 4; ++ss) {
        __syncthreads();   // stage(ss) resident (vmcnt drain); buf^1 free

        if (ss + 1 < 4) {
            const char* gs = gB + (size_t)(ss + 1) * 65536;
            #pragma unroll
            for (int u = 0; u < 8; ++u)
                gload_lds16(gs + (size_t)(u * 512 + tid) * 16,
                            smem + (buf ^ 1) * 65536 + (size_t)(u * 512 + tid) * 16);
        }

        #pragma unroll
        for (int ktl = 0; ktl < 8; ++ktl) {
            const int i  = ss * 8 + ktl;         // kt32 local index 0..31
            const int in = (i + 1 < 32) ? i + 1 : i;

            // issue NEXT iteration's adj (renamed regs, stays in flight)
            const int4v na0 = *(const int4v*)(aptr0 + in * 32);
            const int4v na1 = *(const int4v*)(aptr0 + in * 32 + 4);
            const int4v na2 = *(const int4v*)(aptr1 + in * 32);
            const int4v na3 = *(const int4v*)(aptr1 + in * 32 + 4);

            // f_dst from LDS (no global round-trip on the exp path)
            const f32x4 fd0 = *(const f32x4*)(fdl + i * 32 + g * 8);
            const f32x4 fd1 = *(const f32x4*)(fdl + i * 32 + g * 8 + 4);

            const char* lb = smem + buf * 65536 + ktl * 8192 + (size_t)lane * 16;
            short8v bv[8];
            #pragma unroll
            for (int np = 0; np < 8; ++np)
                bv[np] = *(const short8v*)(lb + np * 1024);

            __builtin_amdgcn_sched_barrier(0);   // pin loads above compute

            float p0[8], p1[8];
            #pragma unroll
            for (int e = 0; e < 4; ++e) {
                float s;
                s = fsrc0 + fd0[e]; s = s > 0.f ? s : 0.2f * s;
                p0[e]     = (ca0[e] != 0) ? __expf(s) : 0.f;
                s = fsrc0 + fd1[e]; s = s > 0.f ? s : 0.2f * s;
                p0[4 + e] = (ca1[e] != 0) ? __expf(s) : 0.f;
                s = fsrc1 + fd0[e]; s = s > 0.f ? s : 0.2f * s;
                p1[e]     = (ca2[e] != 0) ? __expf(s) : 0.f;
                s = fsrc1 + fd1[e]; s = s > 0.f ? s : 0.2f * s;
                p1[4 + e] = (ca3[e] != 0) ? __expf(s) : 0.f;
            }
            psum0 += ((p0[0] + p0[1]) + (p0[2] + p0[3]))
                   + ((p0[4] + p0[5]) + (p0[6] + p0[7]));
            psum1 += ((p1[0] + p1[1]) + (p1[2] + p1[3]))
                   + ((p1[4] + p1[5]) + (p1[6] + p1[7]));
            const short8v af0 = { (short)bf16_bits(p0[0]), (short)bf16_bits(p0[1]),
                                  (short)bf16_bits(p0[2]), (short)bf16_bits(p0[3]),
                                  (short)bf16_bits(p0[4]), (short)bf16_bits(p0[5]),
                                  (short)bf16_bits(p0[6]), (short)bf16_bits(p0[7]) };
            const short8v af1 = { (short)bf16_bits(p1[0]), (short)bf16_bits(p1[1]),
                                  (short)bf16_bits(p1[2]), (short)bf16_bits(p1[3]),
                                  (short)bf16_bits(p1[4]), (short)bf16_bits(p1[5]),
                                  (short)bf16_bits(p1[6]), (short)bf16_bits(p1[7]) };

            #pragma unroll
            for (int np = 0; np < 8; ++np) {
                acc0[np] = mfma32(af0, bv[np], acc0[np]);
                acc1[np] = mfma32(af1, bv[np], acc1[np]);
            }

            ca0 = na0; ca1 = na1; ca2 = na2; ca3 = na3;
        }
        buf ^= 1;
    }

    // rowsum partials: reduce over the 4 g-groups; lanes 0-15 store direct
    psum0 += __shfl_xor(psum0, 16, 64);
    psum0 += __shfl_xor(psum0, 32, 64);
    psum1 += __shfl_xor(psum1, 16, 64);
    psum1 += __shfl_xor(psum1, 32, 64);
    if (lane < 16) {
        rsPart[(size_t)ks * NN + rowbase + w * 32 + lane]      = psum0;
        rsPart[(size_t)ks * NN + rowbase + w * 32 + 16 + lane] = psum1;
    }

    __syncthreads();   // all waves done reading stage buffers

    // wave-private LDS transpose (frag -> row-major 32x128), then coalesced
    float* lt = (float*)(smem + w * 16384);   // 16 KiB per wave
    #pragma unroll
    for (int np = 0; np < 8; ++np)
        #pragma unroll
        for (int q = 0; q < 4; ++q) {
            lt[(4 * g + q) * OF + np * 16 + r]        = acc0[np][q];
            lt[2048 + (4 * g + q) * OF + np * 16 + r] = acc1[np][q];
        }

    float* pb = part + ((size_t)ks * NN + rowbase + w * 32) * OF;
    #pragma unroll
    for (int j = 0; j < 16; ++j) {
        const int idx = j * 64 + lane;       // f32x4 index in 32x128 tile
        *(f32x4*)(pb + (size_t)idx * 4) = *(const f32x4*)&lt[idx * 4];
    }
}

// ---------------------------------------------------------------------------
// Finish: out = relu( (sum_ks part[ks]) / (sum_ks rs[ks]) ).
// ---------------------------------------------------------------------------
__global__ __launch_bounds__(512) void gat_finish(
    const float* __restrict__ part, const float* __restrict__ rsPart,
    float* __restrict__ out)
{
    const int tg  = blockIdx.x * 512 + threadIdx.x;   // f32x4 index
    const int row = tg >> 5;

    f32x4 v = {};
    float den = 0.f;
    #pragma unroll
    for (int ks = 0; ks < 8; ++ks) {
        v   += *(const f32x4*)(part + (size_t)ks * NN * OF + (size_t)tg * 4);
        den += rsPart[(size_t)ks * NN + row];
    }
    const float inv = 1.0f / den;
    f32x4 o = v * inv;
    #pragma unroll
    for (int e = 0; e < 4; ++e) o[e] = fmaxf(o[e], 0.f);
    *(f32x4*)(out + (size_t)tg * 4) = o;
}

extern "C" void kernel_launch(void* const* d_in, const int* in_sizes, int n_in,
                              void* d_out, int out_size, void* d_ws, size_t ws_size,
                              hipStream_t stream) {
    const float* X   = (const float*)d_in[0];
    const int*   adj = (const int*)d_in[1];
    const float* W   = (const float*)d_in[2];
    const float* a   = (const float*)d_in[3];
    float* out = (float*)d_out;

    char* ws = (char*)d_ws;
    unsigned short* HtB    = (unsigned short*)ws;                  // 2 MiB
    float*          f_src  = (float*)(ws + 2097152);               // 32 KiB
    float*          f_dst  = (float*)(ws + 2097152 + 32768);       // 32 KiB
    float*          rsPart = (float*)(ws + 2162688);               // 256 KiB
    float*          part   = (float*)(ws + 2424832);               // 32 MiB

    gat_prep<<<NN / 32, 256, 0, stream>>>(X, W, a, HtB, f_src, f_dst);
    gat_row3c<<<256, 512, 0, stream>>>(adj, (const char*)HtB,
                                       f_src, f_dst, part, rsPart);
    gat_finish<<<512, 512, 0, stream>>>(part, rsPart, out);
}